// Round 17
// baseline (253.157 us; speedup 1.0000x reference)
//
#include <hip/hip_runtime.h>
#include <hip/hip_bf16.h>

#define N_NODES 50000
#define N_EDGES 400000
#define IN_DIM 24
#define HID 256
#define OUT_DIM 12

typedef _Float16 fp16_t;
typedef __attribute__((ext_vector_type(8))) _Float16 half8;
typedef __attribute__((ext_vector_type(4))) float f32x4;

// async global->LDS, 16 bytes per lane (dest must be linear: base + lane*16 per wave)
__device__ __forceinline__ void gload_lds16(const void* g, void* l) {
    typedef __attribute__((address_space(3))) unsigned int u32_lds;
    typedef const __attribute__((address_space(1))) unsigned int u32_glb;
    __builtin_amdgcn_global_load_lds((u32_glb*)(unsigned long long)g,
                                     (u32_lds*)(unsigned int)(unsigned long long)l,
                                     16, 0, 0);
}

// ---------------- shared MFMA GEMM body, BK=64 (single weight plane) ----------------
// Block tile BM x BN, BK=64 (2 kk sub-steps of K=32 MFMA). Waves (BM/64)x(BN/64).
// LDS row stride 64 fp16 = 8 x 16B chunks; swizzle phys=(logical+(row>>1))&7 applied on
// the GLOBAL source (gload_lds dest linear); frag read uses the same involution ->
// 16-lane ds_read_b128 phases are 2-way on banks (free). Halved barrier count vs BK=32.
// MODE 0: A rows from A [N][K];  MODE 1: k<HID from A (mean), else A2 (h), both [N][HID]
template<int K, int MODE, int BM, int BN, bool WH16, bool RELU>
__device__ __forceinline__ void gemm_body(
    const fp16_t* __restrict__ A, const fp16_t* __restrict__ A2,
    const fp16_t* __restrict__ W,
    const float* __restrict__ bias,
    fp16_t* __restrict__ Yh,
    int N, int M, int bx, int by) {
    constexpr int NWR = BM / 64;
    constexpr int NWC = BN / 64;
    constexpr int NT = NWR * NWC * 64;
    __shared__ __align__(16) fp16_t ldsA[BM * 64];
    __shared__ __align__(16) fp16_t ldsB[BN * 64];
    const int tid = threadIdx.x;
    const int r0 = bx * BM;
    const int j0 = by * BN;
    const int w = tid >> 6, lane = tid & 63;
    const int wr = w / NWC, wc = w % NWC;
    const int lrow = lane & 15, lg = lane >> 4;

    f32x4 acc[4][4] = {};

    for (int kc = 0; kc < K; kc += 64) {
        __syncthreads();
        const fp16_t* pa;
        int ka, KA;
        if (MODE == 1) {
            KA = HID;
            if (kc >= HID) { pa = A2; ka = kc - HID; }
            else           { pa = A;  ka = kc; }
        } else {
            KA = K; pa = A; ka = kc;
        }
#pragma unroll
        for (int c = tid; c < BM * 8; c += NT) {
            int row = c >> 3, p = c & 7;
            int g = (p - (row >> 1)) & 7;
            int gr = r0 + row; if (gr > N - 1) gr = N - 1;
            gload_lds16(pa + (size_t)gr * KA + ka + g * 8,
                        (char*)ldsA + (size_t)c * 16);
        }
#pragma unroll
        for (int c = tid; c < BN * 8; c += NT) {
            int row = c >> 3, p = c & 7;
            int g = (p - (row >> 1)) & 7;
            gload_lds16(W + (size_t)(j0 + row) * K + kc + g * 8,
                        (char*)ldsB + (size_t)c * 16);
        }
        __syncthreads();

#pragma unroll
        for (int kk = 0; kk < 2; ++kk) {
            half8 a[4], b[4];
            const int lc = kk * 4 + lg;
#pragma unroll
            for (int f = 0; f < 4; ++f) {
                int ar = wr * 64 + f * 16 + lrow;
                int sa = (lc + (ar >> 1)) & 7;
                a[f] = *(const half8*)&ldsA[ar * 64 + sa * 8];
                int br = wc * 64 + f * 16 + lrow;
                int sb = (lc + (br >> 1)) & 7;
                b[f] = *(const half8*)&ldsB[br * 64 + sb * 8];
            }
#pragma unroll
            for (int fi = 0; fi < 4; ++fi)
#pragma unroll
                for (int fj = 0; fj < 4; ++fj)
                    acc[fi][fj] = __builtin_amdgcn_mfma_f32_16x16x32_f16(a[fi], b[fj], acc[fi][fj], 0, 0, 0);
        }
    }

    // epilogue: C/D layout col=lane&15, row=(lane>>4)*4+reg
#pragma unroll
    for (int fj = 0; fj < 4; ++fj) {
        int ocol = j0 + wc * 64 + fj * 16 + lrow;
        float bv = bias[ocol];
#pragma unroll
        for (int fi = 0; fi < 4; ++fi) {
#pragma unroll
            for (int r = 0; r < 4; ++r) {
                int orow = r0 + wr * 64 + fi * 16 + lg * 4 + r;
                if (orow < N) {
                    float v = acc[fi][fj][r] + bv;
                    if (RELU) v = fmaxf(v, 0.f);
                    if (WH16) Yh[(size_t)orow * M + ocol] = (fp16_t)v;
                }
            }
        }
    }
}

// ---------------- encoder layer 1 body (K=24, f32 compute, fp16 out; 256 thr, 16 rows) ----
__device__ __forceinline__ void enc1_body(const float* __restrict__ X,
                                          const float* __restrict__ W,
                                          const float* __restrict__ b,
                                          fp16_t* __restrict__ Y, int N, int bx) {
    __shared__ float xs[16][IN_DIM];
    const int tid = threadIdx.x;
    const int row0 = bx * 16;
    for (int i = tid; i < 16 * IN_DIM; i += 256) {
        int r = i / IN_DIM, k = i - r * IN_DIM;
        int gr = row0 + r;
        xs[r][k] = (gr < N) ? X[(size_t)gr * IN_DIM + k] : 0.f;
    }
    __syncthreads();
    const int j = tid & 127;
    const int rg = tid >> 7;   // 0/1: rows rg*8 .. rg*8+7
    float acc[8];
    float bj = b[j];
#pragma unroll
    for (int r = 0; r < 8; ++r) acc[r] = bj;
    for (int k = 0; k < IN_DIM; ++k) {
        float w = W[k * 128 + j];
#pragma unroll
        for (int r = 0; r < 8; ++r) acc[r] = fmaf(xs[rg * 8 + r][k], w, acc[r]);
    }
#pragma unroll
    for (int r = 0; r < 8; ++r) {
        int gr = row0 + rg * 8 + r;
        if (gr < N) Y[(size_t)gr * 128 + j] = (fp16_t)fmaxf(acc[r], 0.f);
    }
}

// ---------------- K1: wtrans (+deg zeroing)  ||  lin_enc1 ----------------
__global__ __launch_bounds__(256) void k_prep(
    const float* __restrict__ enc_w2,
    const float* __restrict__ s1_wl, const float* __restrict__ s1_wr,
    const float* __restrict__ s2_wl, const float* __restrict__ s2_wr,
    const float* __restrict__ ro_w1,
    fp16_t* __restrict__ wtE, fp16_t* __restrict__ wtS1,
    fp16_t* __restrict__ wtS2, fp16_t* __restrict__ wtR,
    int* __restrict__ deg,
    const float* __restrict__ X, const float* __restrict__ enc_w1,
    const float* __restrict__ enc_b1, fp16_t* __restrict__ h0,
    int N, int nbW) {
    const int sE = 256 * 128, sS = 256 * 512, sR = 128 * 256;
    if ((int)blockIdx.x < nbW) {
        int idx = blockIdx.x * 256 + threadIdx.x;
        if (idx < N) deg[idx] = 0;
        float v; fp16_t* p; int o;
        if (idx < sE) {
            int j = idx / 128, k = idx - j * 128;
            v = enc_w2[(size_t)k * 256 + j]; p = wtE; o = idx;
        } else if (idx < sE + sS) {
            int t = idx - sE; int j = t / 512, k = t - j * 512;
            v = (k < 256) ? s1_wl[(size_t)k * 256 + j] : s1_wr[(size_t)(k - 256) * 256 + j];
            p = wtS1; o = t;
        } else if (idx < sE + 2 * sS) {
            int t = idx - sE - sS; int j = t / 512, k = t - j * 512;
            v = (k < 256) ? s2_wl[(size_t)k * 256 + j] : s2_wr[(size_t)(k - 256) * 256 + j];
            p = wtS2; o = t;
        } else if (idx < sE + 2 * sS + sR) {
            int t = idx - sE - 2 * sS; int j = t / 256, k = t - j * 256;
            v = ro_w1[(size_t)k * 128 + j]; p = wtR; o = t;
        } else return;
        p[o] = (fp16_t)v;
    } else {
        enc1_body(X, enc_w1, enc_b1, h0, N, blockIdx.x - nbW);
    }
}

// ---------------- K2: encoder MFMA GEMM  ||  degree count ----------------
__global__ __launch_bounds__(512, 3) void k_encgemm_deg(
    const fp16_t* __restrict__ h0, const fp16_t* __restrict__ wtE,
    const float* __restrict__ enc_b2, fp16_t* __restrict__ hA,
    const int* __restrict__ dst, int* __restrict__ deg,
    int N, int E, int nbGemm) {
    if ((int)blockIdx.x < nbGemm) {
        gemm_body<128, 0, 128, 256, true, true>(h0, nullptr, wtE, enc_b2, hA, N, 256,
                                                blockIdx.x, 0);
    } else {
        int e = (blockIdx.x - nbGemm) * 512 + threadIdx.x;
        if (e < E) atomicAdd(&deg[dst[e]], 1);
    }
}

// ---------------- standalone SAGE GEMM ----------------
template<int K, int MODE, int BM, int BN, bool WH16, bool RELU>
__global__ __launch_bounds__((BM / 64) * (BN / 64) * 64, 3) void gemm_mfma(
    const fp16_t* __restrict__ A, const fp16_t* __restrict__ A2,
    const fp16_t* __restrict__ W,
    const float* __restrict__ bias,
    fp16_t* __restrict__ Yh,
    int N, int M) {
    gemm_body<K, MODE, BM, BN, WH16, RELU>(A, A2, W, bias, Yh, N, M, blockIdx.x, blockIdx.y);
}

// ---------------- Fused readout: out = relu(A @ wtR^T + b1) @ W2 + b2 ----------------
__global__ __launch_bounds__(256, 3) void gemm_ro(
    const fp16_t* __restrict__ A,      // hA [N][256]
    const fp16_t* __restrict__ W,      // wtR [128][256]
    const float* __restrict__ b1,
    const float* __restrict__ W2,      // ro_w2 [128][12] f32
    const float* __restrict__ b2,
    float* __restrict__ out, int N) {
    constexpr int K = 256;
    __shared__ __align__(16) fp16_t ldsA[128 * 32];
    __shared__ __align__(16) fp16_t ldsB[128 * 32];
    __shared__ __align__(16) fp16_t htile[128 * 128];
    __shared__ __align__(16) fp16_t w2t[16 * 128];
    const int tid = threadIdx.x;
    const int r0 = blockIdx.x * 128;
    const int w = tid >> 6, lane = tid & 63;
    const int wr = w >> 1, wc = w & 1;
    const int lrow = lane & 15, lg = lane >> 4;

    for (int i = tid; i < 16 * 128; i += 256) {
        int c = i >> 7, k = i & 127;
        w2t[i] = (c < 12) ? (fp16_t)W2[k * 12 + c] : (fp16_t)0.f;
    }

    f32x4 acc[4][4] = {};
    for (int kc = 0; kc < K; kc += 32) {
        __syncthreads();
#pragma unroll
        for (int c = tid; c < 128 * 4; c += 256) {
            int row = c >> 2, p = c & 3;
            int g = (p - (row >> 1)) & 3;
            int gr = r0 + row; if (gr > N - 1) gr = N - 1;
            gload_lds16(A + (size_t)gr * K + kc + g * 8, (char*)ldsA + (size_t)c * 16);
        }
#pragma unroll
        for (int c = tid; c < 128 * 4; c += 256) {
            int row = c >> 2, p = c & 3;
            int g = (p - (row >> 1)) & 3;
            gload_lds16(W + (size_t)row * K + kc + g * 8, (char*)ldsB + (size_t)c * 16);
        }
        __syncthreads();

        half8 a[4], b[4];
#pragma unroll
        for (int f = 0; f < 4; ++f) {
            int ar = wr * 64 + f * 16 + lrow;
            int sa = (lg + (ar >> 1)) & 3;
            a[f] = *(const half8*)&ldsA[ar * 32 + sa * 8];
            int br = wc * 64 + f * 16 + lrow;
            int sb = (lg + (br >> 1)) & 3;
            b[f] = *(const half8*)&ldsB[br * 32 + sb * 8];
        }
#pragma unroll
        for (int fi = 0; fi < 4; ++fi)
#pragma unroll
            for (int fj = 0; fj < 4; ++fj)
                acc[fi][fj] = __builtin_amdgcn_mfma_f32_16x16x32_f16(a[fi], b[fj], acc[fi][fj], 0, 0, 0);
    }

    // epilogue 1: relu(acc + b1) -> htile (swizzled fp16)
#pragma unroll
    for (int fj = 0; fj < 4; ++fj) {
        int ocol = wc * 64 + fj * 16 + lrow;
        float bv = b1[ocol];
        int q = ocol >> 3;
#pragma unroll
        for (int fi = 0; fi < 4; ++fi) {
#pragma unroll
            for (int r = 0; r < 4; ++r) {
                int orow = wr * 64 + fi * 16 + lg * 4 + r;
                float v = fmaxf(acc[fi][fj][r] + bv, 0.f);
                int phys = (q + (orow >> 1)) & 15;
                htile[orow * 128 + phys * 8 + (ocol & 7)] = (fp16_t)v;
            }
        }
    }
    __syncthreads();

    // final: out(128x12) = htile(128x128) @ W2(128x12); waves 0-1, 64 rows each
    if (w < 2) {
        f32x4 accF[4] = {};
#pragma unroll
        for (int kt = 0; kt < 4; ++kt) {
            half8 bb = *(const half8*)&w2t[lrow * 128 + kt * 32 + lg * 8];
            half8 a[4];
#pragma unroll
            for (int f = 0; f < 4; ++f) {
                int ar = w * 64 + f * 16 + lrow;
                int q = kt * 4 + lg;
                int phys = (q + (ar >> 1)) & 15;
                a[f] = *(const half8*)&htile[ar * 128 + phys * 8];
            }
#pragma unroll
            for (int f = 0; f < 4; ++f)
                accF[f] = __builtin_amdgcn_mfma_f32_16x16x32_f16(a[f], bb, accF[f], 0, 0, 0);
        }
        if (lrow < OUT_DIM) {
            float bv = b2[lrow];
#pragma unroll
            for (int f = 0; f < 4; ++f) {
#pragma unroll
                for (int r = 0; r < 4; ++r) {
                    int orow = r0 + w * 64 + f * 16 + lg * 4 + r;
                    if (orow < N) out[(size_t)orow * OUT_DIM + lrow] = accF[f][r] + bv;
                }
            }
        }
    }
}

// Stage 1: per-block inclusive scan (256 elems/block) + block total
__global__ __launch_bounds__(256) void scan_local(const int* __restrict__ deg,
                                                  int* __restrict__ locincl,
                                                  int* __restrict__ bsum, int N) {
    const int t = threadIdx.x;
    const int i = blockIdx.x * 256 + t;
    int v = (i < N) ? deg[i] : 0;
    const int lane = t & 63;
    int x = v;
#pragma unroll
    for (int off = 1; off < 64; off <<= 1) {
        int y = __shfl_up(x, off, 64);
        if (lane >= off) x += y;
    }
    __shared__ int wsum[4];
    if (lane == 63) wsum[t >> 6] = x;
    __syncthreads();
    const int wid = t >> 6;
    int add = 0;
    for (int wI = 0; wI < wid; ++wI) add += wsum[wI];
    x += add;
    if (i < N) locincl[i] = x;
    if (t == 255) bsum[blockIdx.x] = x;
}

// Stage 2: each block reduces bsum[0..blockIdx.x) itself, writes exclusive rowptr + cursor.
__global__ __launch_bounds__(256) void scan_final(const int* __restrict__ deg,
                                                  const int* __restrict__ locincl,
                                                  const int* __restrict__ bsum,
                                                  int* __restrict__ rowptr,
                                                  int* __restrict__ cursor,
                                                  int N, int E, int B) {
    __shared__ int red[4];
    const int t = threadIdx.x;
    int s = (t < blockIdx.x && t < B) ? bsum[t] : 0;
#pragma unroll
    for (int off = 32; off > 0; off >>= 1) s += __shfl_down(s, off, 64);
    if ((t & 63) == 0) red[t >> 6] = s;
    __syncthreads();
    int base = red[0] + red[1] + red[2] + red[3];
    const int i = blockIdx.x * 256 + t;
    if (i < N) {
        int excl = base + locincl[i] - deg[i];
        rowptr[i] = excl;
        cursor[i] = excl;
    }
    if (i == 0) rowptr[N] = E;
}

__global__ void scatter_kernel(const int* __restrict__ src, const int* __restrict__ dst,
                               int* __restrict__ cursor, int* __restrict__ esrc, int E) {
    int e = blockIdx.x * blockDim.x + threadIdx.x;
    if (e < E) {
        int pos = atomicAdd(&cursor[dst[e]], 1);
        esrc[pos] = src[e];
    }
}

// ---------------- CSR mean-aggregation: wave-per-node, 16B/lane gathers ----------------
__global__ __launch_bounds__(256) void agg_csr(const fp16_t* __restrict__ h,
                                               const int* __restrict__ rowptr,
                                               const int* __restrict__ esrc,
                                               fp16_t* __restrict__ mean, int N) {
    const int n = blockIdx.x * 4 + (threadIdx.x >> 6);
    if (n >= N) return;
    const int lane = threadIdx.x & 63;
    const int half = lane >> 5;         // 0 or 1
    const int l32 = lane & 31;          // channel group 0..31 (8 ch each)
    const int r0 = rowptr[n];
    const int r1 = rowptr[n + 1];
    const int deg = r1 - r0;

    float acc[8];
#pragma unroll
    for (int j = 0; j < 8; ++j) acc[j] = 0.f;

    for (int e = r0 + half; e < r1; e += 2) {
        int s = esrc[e];
        half8 v = *(const half8*)&h[(size_t)s * HID + l32 * 8];
#pragma unroll
        for (int j = 0; j < 8; ++j) acc[j] += (float)v[j];
    }
#pragma unroll
    for (int j = 0; j < 8; ++j) acc[j] += __shfl(acc[j], lane ^ 32, 64);

    if (half == 0) {
        float inv = 1.0f / fmaxf((float)deg, 1.0f);
        half8 o;
#pragma unroll
        for (int j = 0; j < 8; ++j) o[j] = (fp16_t)(acc[j] * inv);
        *(half8*)&mean[(size_t)n * HID + l32 * 8] = o;
    }
}

extern "C" void kernel_launch(void* const* d_in, const int* in_sizes, int n_in,
                              void* d_out, int out_size, void* d_ws, size_t ws_size,
                              hipStream_t stream) {
    const float* x      = (const float*)d_in[0];
    const int*   eidx   = (const int*)d_in[1];
    const float* enc_w1 = (const float*)d_in[2];
    const float* enc_b1 = (const float*)d_in[3];
    const float* enc_w2 = (const float*)d_in[4];
    const float* enc_b2 = (const float*)d_in[5];
    const float* s1_wl  = (const float*)d_in[6];
    const float* s1_bl  = (const float*)d_in[7];
    const float* s1_wr  = (const float*)d_in[8];
    const float* s2_wl  = (const float*)d_in[9];
    const float* s2_bl  = (const float*)d_in[10];
    const float* s2_wr  = (const float*)d_in[11];
    const float* ro_w1  = (const float*)d_in[12];
    const float* ro_b1  = (const float*)d_in[13];
    const float* ro_w2  = (const float*)d_in[14];
    const float* ro_b2  = (const float*)d_in[15];
    float* out = (float*)d_out;

    const int N = N_NODES;
    const int E = N_EDGES;
    const int* src = eidx;
    const int* dst = eidx + E;

    char* ws = (char*)d_ws;
    size_t off = 0;
    auto alloc = [&](size_t bytes) { void* p = ws + off; off += (bytes + 255) & ~255ULL; return p; };
    int* deg     = (int*)alloc((size_t)N * 4);
    int* rowptr  = (int*)alloc((size_t)(N + 1) * 4);
    int* cursor  = (int*)alloc((size_t)N * 4);
    int* esrc    = (int*)alloc((size_t)E * 4);
    int* locincl = (int*)alloc((size_t)N * 4);
    int* bsum    = (int*)alloc((size_t)256 * 4);
    fp16_t* wtE  = (fp16_t*)alloc((size_t)256 * 128 * 2);
    fp16_t* wtS1 = (fp16_t*)alloc((size_t)256 * 512 * 2);
    fp16_t* wtS2 = (fp16_t*)alloc((size_t)256 * 512 * 2);
    fp16_t* wtR  = (fp16_t*)alloc((size_t)128 * 256 * 2);
    fp16_t* h0   = (fp16_t*)alloc((size_t)N * 128 * 2);
    fp16_t* hA   = (fp16_t*)alloc((size_t)N * HID * 2);
    fp16_t* hB   = (fp16_t*)alloc((size_t)N * HID * 2);
    fp16_t* mbuf = (fp16_t*)alloc((size_t)N * HID * 2);

    const int gx128 = (N + 127) / 128;
    const int nbScan = (N + 255) / 256;
    const int nbAgg = (N + 3) / 4;
    const int wtTot = 256 * 128 + 2 * 256 * 512 + 128 * 256;
    const int nbW = (wtTot + 255) / 256;           // 1568
    const int nbEnc = (N + 15) / 16;               // 3125
    const int nbDeg512 = (E + 511) / 512;          // 782

    // ---- K1: wtrans (+deg zero)  ||  lin_enc1 ----
    k_prep<<<nbW + nbEnc, 256, 0, stream>>>(
        enc_w2, s1_wl, s1_wr, s2_wl, s2_wr, ro_w1,
        wtE, wtS1, wtS2, wtR, deg, x, enc_w1, enc_b1, h0, N, nbW);

    // ---- K2: encoder GEMM  ||  degree count ----
    k_encgemm_deg<<<gx128 + nbDeg512, 512, 0, stream>>>(
        h0, wtE, enc_b2, hA, dst, deg, N, E, gx128);

    // ---- CSR scan + scatter ----
    scan_local<<<nbScan, 256, 0, stream>>>(deg, locincl, bsum, N);
    scan_final<<<nbScan, 256, 0, stream>>>(deg, locincl, bsum, rowptr, cursor, N, E, nbScan);
    scatter_kernel<<<(E + 255) / 256, 256, 0, stream>>>(src, dst, cursor, esrc, E);

    // ---- SAGE 1 ----
    agg_csr<<<nbAgg, 256, 0, stream>>>(hA, rowptr, esrc, mbuf, N);
    gemm_mfma<512, 1, 128, 256, true, true><<<dim3(gx128, 1), 512, 0, stream>>>(
        mbuf, hA, wtS1, s1_bl, hB, N, 256);

    // ---- SAGE 2 ----
    agg_csr<<<nbAgg, 256, 0, stream>>>(hB, rowptr, esrc, mbuf, N);
    gemm_mfma<512, 1, 128, 256, true, true><<<dim3(gx128, 1), 512, 0, stream>>>(
        mbuf, hB, wtS2, s2_bl, hA, N, 256);

    // ---- fused readout ----
    gemm_ro<<<gx128, 256, 0, stream>>>(hA, wtR, ro_b1, ro_w2, ro_b2, out, N);
}

// Round 18
// 221.548 us; speedup vs baseline: 1.1427x; 1.1427x over previous
//
#include <hip/hip_runtime.h>
#include <hip/hip_bf16.h>

#define N_NODES 50000
#define N_EDGES 400000
#define IN_DIM 24
#define HID 256
#define OUT_DIM 12

typedef _Float16 fp16_t;
typedef __attribute__((ext_vector_type(8))) _Float16 half8;
typedef __attribute__((ext_vector_type(4))) float f32x4;

// async global->LDS, 16 bytes per lane (dest must be linear: base + lane*16 per wave)
__device__ __forceinline__ void gload_lds16(const void* g, void* l) {
    typedef __attribute__((address_space(3))) unsigned int u32_lds;
    typedef const __attribute__((address_space(1))) unsigned int u32_glb;
    __builtin_amdgcn_global_load_lds((u32_glb*)(unsigned long long)g,
                                     (u32_lds*)(unsigned int)(unsigned long long)l,
                                     16, 0, 0);
}

// ---------------- shared MFMA GEMM body (single weight plane, BK=32) ----------------
// Block tile BM x BN. Waves (BM/64)x(BN/64), wave tile 64x64 (4x4 frags 16x16x32).
// LDS 16B-chunk swizzle (verified R11/R12, conflicts=0): phys slot p of row holds logical
// chunk (p-(row>>1))&3 applied on the GLOBAL source; frag read slot=(lg+(row>>1))&3.
// MODE 0: A rows from A [N][K];  MODE 1: k<HID from A (mean), else A2 (h), both [N][HID]
template<int K, int MODE, int BM, int BN, bool WH16, bool RELU>
__device__ __forceinline__ void gemm_body(
    const fp16_t* __restrict__ A, const fp16_t* __restrict__ A2,
    const fp16_t* __restrict__ W,
    const float* __restrict__ bias,
    fp16_t* __restrict__ Yh,
    int N, int M, int bx, int by) {
    constexpr int NWR = BM / 64;
    constexpr int NWC = BN / 64;
    constexpr int NT = NWR * NWC * 64;
    __shared__ __align__(16) fp16_t ldsA[BM * 32];
    __shared__ __align__(16) fp16_t ldsB[BN * 32];
    const int tid = threadIdx.x;
    const int r0 = bx * BM;
    const int j0 = by * BN;
    const int w = tid >> 6, lane = tid & 63;
    const int wr = w / NWC, wc = w % NWC;
    const int lrow = lane & 15, lg = lane >> 4;

    f32x4 acc[4][4] = {};

    for (int kc = 0; kc < K; kc += 32) {
        __syncthreads();
        const fp16_t* pa;
        int ka, KA;
        if (MODE == 1) {
            KA = HID;
            if (kc >= HID) { pa = A2; ka = kc - HID; }
            else           { pa = A;  ka = kc; }
        } else {
            KA = K; pa = A; ka = kc;
        }
#pragma unroll
        for (int c = tid; c < BM * 4; c += NT) {
            int row = c >> 2, p = c & 3;
            int g = (p - (row >> 1)) & 3;
            int gr = r0 + row; if (gr > N - 1) gr = N - 1;
            gload_lds16(pa + (size_t)gr * KA + ka + g * 8,
                        (char*)ldsA + (size_t)c * 16);
        }
#pragma unroll
        for (int c = tid; c < BN * 4; c += NT) {
            int row = c >> 2, p = c & 3;
            int g = (p - (row >> 1)) & 3;
            gload_lds16(W + (size_t)(j0 + row) * K + kc + g * 8,
                        (char*)ldsB + (size_t)c * 16);
        }
        __syncthreads();

        half8 a[4], b[4];
#pragma unroll
        for (int f = 0; f < 4; ++f) {
            int ar = wr * 64 + f * 16 + lrow;
            int sa = (lg + (ar >> 1)) & 3;
            a[f] = *(const half8*)&ldsA[ar * 32 + sa * 8];
            int br = wc * 64 + f * 16 + lrow;
            int sb = (lg + (br >> 1)) & 3;
            b[f] = *(const half8*)&ldsB[br * 32 + sb * 8];
        }
#pragma unroll
        for (int fi = 0; fi < 4; ++fi)
#pragma unroll
            for (int fj = 0; fj < 4; ++fj)
                acc[fi][fj] = __builtin_amdgcn_mfma_f32_16x16x32_f16(a[fi], b[fj], acc[fi][fj], 0, 0, 0);
    }

    // epilogue: C/D layout col=lane&15, row=(lane>>4)*4+reg
#pragma unroll
    for (int fj = 0; fj < 4; ++fj) {
        int ocol = j0 + wc * 64 + fj * 16 + lrow;
        float bv = bias[ocol];
#pragma unroll
        for (int fi = 0; fi < 4; ++fi) {
#pragma unroll
            for (int r = 0; r < 4; ++r) {
                int orow = r0 + wr * 64 + fi * 16 + lg * 4 + r;
                if (orow < N) {
                    float v = acc[fi][fj][r] + bv;
                    if (RELU) v = fmaxf(v, 0.f);
                    if (WH16) Yh[(size_t)orow * M + ocol] = (fp16_t)v;
                }
            }
        }
    }
}

// ---------------- encoder layer 1 body (K=24, f32 compute, fp16 out; 256 thr, 16 rows) ----
__device__ __forceinline__ void enc1_body(const float* __restrict__ X,
                                          const float* __restrict__ W,
                                          const float* __restrict__ b,
                                          fp16_t* __restrict__ Y, int N, int bx) {
    __shared__ float xs[16][IN_DIM];
    const int tid = threadIdx.x;
    const int row0 = bx * 16;
    for (int i = tid; i < 16 * IN_DIM; i += 256) {
        int r = i / IN_DIM, k = i - r * IN_DIM;
        int gr = row0 + r;
        xs[r][k] = (gr < N) ? X[(size_t)gr * IN_DIM + k] : 0.f;
    }
    __syncthreads();
    const int j = tid & 127;
    const int rg = tid >> 7;   // 0/1: rows rg*8 .. rg*8+7
    float acc[8];
    float bj = b[j];
#pragma unroll
    for (int r = 0; r < 8; ++r) acc[r] = bj;
    for (int k = 0; k < IN_DIM; ++k) {
        float w = W[k * 128 + j];
#pragma unroll
        for (int r = 0; r < 8; ++r) acc[r] = fmaf(xs[rg * 8 + r][k], w, acc[r]);
    }
#pragma unroll
    for (int r = 0; r < 8; ++r) {
        int gr = row0 + rg * 8 + r;
        if (gr < N) Y[(size_t)gr * 128 + j] = (fp16_t)fmaxf(acc[r], 0.f);
    }
}

// ---------------- K1: wtrans (+deg zeroing)  ||  lin_enc1 ----------------
__global__ __launch_bounds__(256) void k_prep(
    const float* __restrict__ enc_w2,
    const float* __restrict__ s1_wl, const float* __restrict__ s1_wr,
    const float* __restrict__ s2_wl, const float* __restrict__ s2_wr,
    const float* __restrict__ ro_w1,
    fp16_t* __restrict__ wtE, fp16_t* __restrict__ wtS1,
    fp16_t* __restrict__ wtS2, fp16_t* __restrict__ wtR,
    int* __restrict__ deg,
    const float* __restrict__ X, const float* __restrict__ enc_w1,
    const float* __restrict__ enc_b1, fp16_t* __restrict__ h0,
    int N, int nbW) {
    const int sE = 256 * 128, sS = 256 * 512, sR = 128 * 256;
    if ((int)blockIdx.x < nbW) {
        int idx = blockIdx.x * 256 + threadIdx.x;
        if (idx < N) deg[idx] = 0;
        float v; fp16_t* p; int o;
        if (idx < sE) {
            int j = idx / 128, k = idx - j * 128;
            v = enc_w2[(size_t)k * 256 + j]; p = wtE; o = idx;
        } else if (idx < sE + sS) {
            int t = idx - sE; int j = t / 512, k = t - j * 512;
            v = (k < 256) ? s1_wl[(size_t)k * 256 + j] : s1_wr[(size_t)(k - 256) * 256 + j];
            p = wtS1; o = t;
        } else if (idx < sE + 2 * sS) {
            int t = idx - sE - sS; int j = t / 512, k = t - j * 512;
            v = (k < 256) ? s2_wl[(size_t)k * 256 + j] : s2_wr[(size_t)(k - 256) * 256 + j];
            p = wtS2; o = t;
        } else if (idx < sE + 2 * sS + sR) {
            int t = idx - sE - 2 * sS; int j = t / 256, k = t - j * 256;
            v = ro_w1[(size_t)k * 128 + j]; p = wtR; o = t;
        } else return;
        p[o] = (fp16_t)v;
    } else {
        enc1_body(X, enc_w1, enc_b1, h0, N, blockIdx.x - nbW);
    }
}

// ---------------- K2: encoder MFMA GEMM  ||  degree count ----------------
__global__ __launch_bounds__(512, 4) void k_encgemm_deg(
    const fp16_t* __restrict__ h0, const fp16_t* __restrict__ wtE,
    const float* __restrict__ enc_b2, fp16_t* __restrict__ hA,
    const int* __restrict__ dst, int* __restrict__ deg,
    int N, int E, int nbGemm) {
    if ((int)blockIdx.x < nbGemm) {
        gemm_body<128, 0, 128, 256, true, true>(h0, nullptr, wtE, enc_b2, hA, N, 256,
                                                blockIdx.x, 0);
    } else {
        int e = (blockIdx.x - nbGemm) * 512 + threadIdx.x;
        if (e < E) atomicAdd(&deg[dst[e]], 1);
    }
}

// ---------------- standalone SAGE GEMM ----------------
template<int K, int MODE, int BM, int BN, bool WH16, bool RELU>
__global__ __launch_bounds__((BM / 64) * (BN / 64) * 64, 4) void gemm_mfma(
    const fp16_t* __restrict__ A, const fp16_t* __restrict__ A2,
    const fp16_t* __restrict__ W,
    const float* __restrict__ bias,
    fp16_t* __restrict__ Yh,
    int N, int M) {
    gemm_body<K, MODE, BM, BN, WH16, RELU>(A, A2, W, bias, Yh, N, M, blockIdx.x, blockIdx.y);
}

// ---------------- Fused readout: out = relu(A @ wtR^T + b1) @ W2 + b2 ----------------
__global__ __launch_bounds__(256, 3) void gemm_ro(
    const fp16_t* __restrict__ A,      // hA [N][256]
    const fp16_t* __restrict__ W,      // wtR [128][256]
    const float* __restrict__ b1,
    const float* __restrict__ W2,      // ro_w2 [128][12] f32
    const float* __restrict__ b2,
    float* __restrict__ out, int N) {
    constexpr int K = 256;
    __shared__ __align__(16) fp16_t ldsA[128 * 32];
    __shared__ __align__(16) fp16_t ldsB[128 * 32];
    __shared__ __align__(16) fp16_t htile[128 * 128];
    __shared__ __align__(16) fp16_t w2t[16 * 128];
    const int tid = threadIdx.x;
    const int r0 = blockIdx.x * 128;
    const int w = tid >> 6, lane = tid & 63;
    const int wr = w >> 1, wc = w & 1;
    const int lrow = lane & 15, lg = lane >> 4;

    for (int i = tid; i < 16 * 128; i += 256) {
        int c = i >> 7, k = i & 127;
        w2t[i] = (c < 12) ? (fp16_t)W2[k * 12 + c] : (fp16_t)0.f;
    }

    f32x4 acc[4][4] = {};
    for (int kc = 0; kc < K; kc += 32) {
        __syncthreads();
#pragma unroll
        for (int c = tid; c < 128 * 4; c += 256) {
            int row = c >> 2, p = c & 3;
            int g = (p - (row >> 1)) & 3;
            int gr = r0 + row; if (gr > N - 1) gr = N - 1;
            gload_lds16(A + (size_t)gr * K + kc + g * 8, (char*)ldsA + (size_t)c * 16);
        }
#pragma unroll
        for (int c = tid; c < 128 * 4; c += 256) {
            int row = c >> 2, p = c & 3;
            int g = (p - (row >> 1)) & 3;
            gload_lds16(W + (size_t)row * K + kc + g * 8, (char*)ldsB + (size_t)c * 16);
        }
        __syncthreads();

        half8 a[4], b[4];
#pragma unroll
        for (int f = 0; f < 4; ++f) {
            int ar = wr * 64 + f * 16 + lrow;
            int sa = (lg + (ar >> 1)) & 3;
            a[f] = *(const half8*)&ldsA[ar * 32 + sa * 8];
            int br = wc * 64 + f * 16 + lrow;
            int sb = (lg + (br >> 1)) & 3;
            b[f] = *(const half8*)&ldsB[br * 32 + sb * 8];
        }
#pragma unroll
        for (int fi = 0; fi < 4; ++fi)
#pragma unroll
            for (int fj = 0; fj < 4; ++fj)
                acc[fi][fj] = __builtin_amdgcn_mfma_f32_16x16x32_f16(a[fi], b[fj], acc[fi][fj], 0, 0, 0);
    }

    // epilogue 1: relu(acc + b1) -> htile (swizzled fp16)
#pragma unroll
    for (int fj = 0; fj < 4; ++fj) {
        int ocol = wc * 64 + fj * 16 + lrow;
        float bv = b1[ocol];
        int q = ocol >> 3;
#pragma unroll
        for (int fi = 0; fi < 4; ++fi) {
#pragma unroll
            for (int r = 0; r < 4; ++r) {
                int orow = wr * 64 + fi * 16 + lg * 4 + r;
                float v = fmaxf(acc[fi][fj][r] + bv, 0.f);
                int phys = (q + (orow >> 1)) & 15;
                htile[orow * 128 + phys * 8 + (ocol & 7)] = (fp16_t)v;
            }
        }
    }
    __syncthreads();

    // final: out(128x12) = htile(128x128) @ W2(128x12); waves 0-1, 64 rows each
    if (w < 2) {
        f32x4 accF[4] = {};
#pragma unroll
        for (int kt = 0; kt < 4; ++kt) {
            half8 bb = *(const half8*)&w2t[lrow * 128 + kt * 32 + lg * 8];
            half8 a[4];
#pragma unroll
            for (int f = 0; f < 4; ++f) {
                int ar = w * 64 + f * 16 + lrow;
                int q = kt * 4 + lg;
                int phys = (q + (ar >> 1)) & 15;
                a[f] = *(const half8*)&htile[ar * 128 + phys * 8];
            }
#pragma unroll
            for (int f = 0; f < 4; ++f)
                accF[f] = __builtin_amdgcn_mfma_f32_16x16x32_f16(a[f], bb, accF[f], 0, 0, 0);
        }
        if (lrow < OUT_DIM) {
            float bv = b2[lrow];
#pragma unroll
            for (int f = 0; f < 4; ++f) {
#pragma unroll
                for (int r = 0; r < 4; ++r) {
                    int orow = r0 + w * 64 + f * 16 + lg * 4 + r;
                    if (orow < N) out[(size_t)orow * OUT_DIM + lrow] = accF[f][r] + bv;
                }
            }
        }
    }
}

// Stage 1: per-block inclusive scan (256 elems/block) + block total
__global__ __launch_bounds__(256) void scan_local(const int* __restrict__ deg,
                                                  int* __restrict__ locincl,
                                                  int* __restrict__ bsum, int N) {
    const int t = threadIdx.x;
    const int i = blockIdx.x * 256 + t;
    int v = (i < N) ? deg[i] : 0;
    const int lane = t & 63;
    int x = v;
#pragma unroll
    for (int off = 1; off < 64; off <<= 1) {
        int y = __shfl_up(x, off, 64);
        if (lane >= off) x += y;
    }
    __shared__ int wsum[4];
    if (lane == 63) wsum[t >> 6] = x;
    __syncthreads();
    const int wid = t >> 6;
    int add = 0;
    for (int wI = 0; wI < wid; ++wI) add += wsum[wI];
    x += add;
    if (i < N) locincl[i] = x;
    if (t == 255) bsum[blockIdx.x] = x;
}

// Stage 2: each block reduces bsum[0..blockIdx.x) itself, writes exclusive rowptr + cursor.
__global__ __launch_bounds__(256) void scan_final(const int* __restrict__ deg,
                                                  const int* __restrict__ locincl,
                                                  const int* __restrict__ bsum,
                                                  int* __restrict__ rowptr,
                                                  int* __restrict__ cursor,
                                                  int N, int E, int B) {
    __shared__ int red[4];
    const int t = threadIdx.x;
    int s = (t < blockIdx.x && t < B) ? bsum[t] : 0;
#pragma unroll
    for (int off = 32; off > 0; off >>= 1) s += __shfl_down(s, off, 64);
    if ((t & 63) == 0) red[t >> 6] = s;
    __syncthreads();
    int base = red[0] + red[1] + red[2] + red[3];
    const int i = blockIdx.x * 256 + t;
    if (i < N) {
        int excl = base + locincl[i] - deg[i];
        rowptr[i] = excl;
        cursor[i] = excl;
    }
    if (i == 0) rowptr[N] = E;
}

__global__ void scatter_kernel(const int* __restrict__ src, const int* __restrict__ dst,
                               int* __restrict__ cursor, int* __restrict__ esrc, int E) {
    int e = blockIdx.x * blockDim.x + threadIdx.x;
    if (e < E) {
        int pos = atomicAdd(&cursor[dst[e]], 1);
        esrc[pos] = src[e];
    }
}

// ---------------- CSR mean-aggregation: wave-per-node, 16B/lane gathers ----------------
__global__ __launch_bounds__(256) void agg_csr(const fp16_t* __restrict__ h,
                                               const int* __restrict__ rowptr,
                                               const int* __restrict__ esrc,
                                               fp16_t* __restrict__ mean, int N) {
    const int n = blockIdx.x * 4 + (threadIdx.x >> 6);
    if (n >= N) return;
    const int lane = threadIdx.x & 63;
    const int half = lane >> 5;         // 0 or 1
    const int l32 = lane & 31;          // channel group 0..31 (8 ch each)
    const int r0 = rowptr[n];
    const int r1 = rowptr[n + 1];
    const int deg = r1 - r0;

    float acc[8];
#pragma unroll
    for (int j = 0; j < 8; ++j) acc[j] = 0.f;

    for (int e = r0 + half; e < r1; e += 2) {
        int s = esrc[e];
        half8 v = *(const half8*)&h[(size_t)s * HID + l32 * 8];
#pragma unroll
        for (int j = 0; j < 8; ++j) acc[j] += (float)v[j];
    }
#pragma unroll
    for (int j = 0; j < 8; ++j) acc[j] += __shfl(acc[j], lane ^ 32, 64);

    if (half == 0) {
        float inv = 1.0f / fmaxf((float)deg, 1.0f);
        half8 o;
#pragma unroll
        for (int j = 0; j < 8; ++j) o[j] = (fp16_t)(acc[j] * inv);
        *(half8*)&mean[(size_t)n * HID + l32 * 8] = o;
    }
}

extern "C" void kernel_launch(void* const* d_in, const int* in_sizes, int n_in,
                              void* d_out, int out_size, void* d_ws, size_t ws_size,
                              hipStream_t stream) {
    const float* x      = (const float*)d_in[0];
    const int*   eidx   = (const int*)d_in[1];
    const float* enc_w1 = (const float*)d_in[2];
    const float* enc_b1 = (const float*)d_in[3];
    const float* enc_w2 = (const float*)d_in[4];
    const float* enc_b2 = (const float*)d_in[5];
    const float* s1_wl  = (const float*)d_in[6];
    const float* s1_bl  = (const float*)d_in[7];
    const float* s1_wr  = (const float*)d_in[8];
    const float* s2_wl  = (const float*)d_in[9];
    const float* s2_bl  = (const float*)d_in[10];
    const float* s2_wr  = (const float*)d_in[11];
    const float* ro_w1  = (const float*)d_in[12];
    const float* ro_b1  = (const float*)d_in[13];
    const float* ro_w2  = (const float*)d_in[14];
    const float* ro_b2  = (const float*)d_in[15];
    float* out = (float*)d_out;

    const int N = N_NODES;
    const int E = N_EDGES;
    const int* src = eidx;
    const int* dst = eidx + E;

    char* ws = (char*)d_ws;
    size_t off = 0;
    auto alloc = [&](size_t bytes) { void* p = ws + off; off += (bytes + 255) & ~255ULL; return p; };
    int* deg     = (int*)alloc((size_t)N * 4);
    int* rowptr  = (int*)alloc((size_t)(N + 1) * 4);
    int* cursor  = (int*)alloc((size_t)N * 4);
    int* esrc    = (int*)alloc((size_t)E * 4);
    int* locincl = (int*)alloc((size_t)N * 4);
    int* bsum    = (int*)alloc((size_t)256 * 4);
    fp16_t* wtE  = (fp16_t*)alloc((size_t)256 * 128 * 2);
    fp16_t* wtS1 = (fp16_t*)alloc((size_t)256 * 512 * 2);
    fp16_t* wtS2 = (fp16_t*)alloc((size_t)256 * 512 * 2);
    fp16_t* wtR  = (fp16_t*)alloc((size_t)128 * 256 * 2);
    fp16_t* h0   = (fp16_t*)alloc((size_t)N * 128 * 2);
    fp16_t* hA   = (fp16_t*)alloc((size_t)N * HID * 2);
    fp16_t* hB   = (fp16_t*)alloc((size_t)N * HID * 2);
    fp16_t* mbuf = (fp16_t*)alloc((size_t)N * HID * 2);

    const int gx128 = (N + 127) / 128;
    const int nbScan = (N + 255) / 256;
    const int nbAgg = (N + 3) / 4;
    const int wtTot = 256 * 128 + 2 * 256 * 512 + 128 * 256;
    const int nbW = (wtTot + 255) / 256;           // 1568
    const int nbEnc = (N + 15) / 16;               // 3125
    const int nbDeg512 = (E + 511) / 512;          // 782

    // ---- K1: wtrans (+deg zero)  ||  lin_enc1 ----
    k_prep<<<nbW + nbEnc, 256, 0, stream>>>(
        enc_w2, s1_wl, s1_wr, s2_wl, s2_wr, ro_w1,
        wtE, wtS1, wtS2, wtR, deg, x, enc_w1, enc_b1, h0, N, nbW);

    // ---- K2: encoder GEMM  ||  degree count ----
    k_encgemm_deg<<<gx128 + nbDeg512, 512, 0, stream>>>(
        h0, wtE, enc_b2, hA, dst, deg, N, E, gx128);

    // ---- CSR scan + scatter ----
    scan_local<<<nbScan, 256, 0, stream>>>(deg, locincl, bsum, N);
    scan_final<<<nbScan, 256, 0, stream>>>(deg, locincl, bsum, rowptr, cursor, N, E, nbScan);
    scatter_kernel<<<(E + 255) / 256, 256, 0, stream>>>(src, dst, cursor, esrc, E);

    // ---- SAGE 1 ----
    agg_csr<<<nbAgg, 256, 0, stream>>>(hA, rowptr, esrc, mbuf, N);
    gemm_mfma<512, 1, 128, 256, true, true><<<dim3(gx128, 1), 512, 0, stream>>>(
        mbuf, hA, wtS1, s1_bl, hB, N, 256);

    // ---- SAGE 2 ----
    agg_csr<<<nbAgg, 256, 0, stream>>>(hB, rowptr, esrc, mbuf, N);
    gemm_mfma<512, 1, 128, 256, true, true><<<dim3(gx128, 1), 512, 0, stream>>>(
        mbuf, hB, wtS2, s2_bl, hA, N, 256);

    // ---- fused readout ----
    gemm_ro<<<gx128, 256, 0, stream>>>(hA, wtR, ro_b1, ro_w2, ro_b2, out, N);
}

// Round 19
// 217.958 us; speedup vs baseline: 1.1615x; 1.0165x over previous
//
#include <hip/hip_runtime.h>
#include <hip/hip_bf16.h>

#define N_NODES 50000
#define N_EDGES 400000
#define IN_DIM 24
#define HID 256
#define OUT_DIM 12

typedef _Float16 fp16_t;
typedef __attribute__((ext_vector_type(8))) _Float16 half8;
typedef __attribute__((ext_vector_type(4))) float f32x4;

// async global->LDS, 16 bytes per lane (dest must be linear: base + lane*16 per wave)
__device__ __forceinline__ void gload_lds16(const void* g, void* l) {
    typedef __attribute__((address_space(3))) unsigned int u32_lds;
    typedef const __attribute__((address_space(1))) unsigned int u32_glb;
    __builtin_amdgcn_global_load_lds((u32_glb*)(unsigned long long)g,
                                     (u32_lds*)(unsigned int)(unsigned long long)l,
                                     16, 0, 0);
}

// ---------------- shared MFMA GEMM body (single weight plane, BK=32) ----------------
// Block tile BM x BN. Waves (BM/64)x(BN/64), wave tile 64x64 (4x4 frags 16x16x32).
// LDS 16B-chunk swizzle (verified R11/R12, conflicts=0): phys slot p of row holds logical
// chunk (p-(row>>1))&3 applied on the GLOBAL source; frag read slot=(lg+(row>>1))&3.
// MODE 0: A rows from A [N][K];  MODE 1: k<HID from A (mean), else A2 (h), both [N][HID]
template<int K, int MODE, int BM, int BN, bool WH16, bool RELU>
__device__ __forceinline__ void gemm_body(
    const fp16_t* __restrict__ A, const fp16_t* __restrict__ A2,
    const fp16_t* __restrict__ W,
    const float* __restrict__ bias,
    fp16_t* __restrict__ Yh,
    int N, int M, int bx, int by) {
    constexpr int NWR = BM / 64;
    constexpr int NWC = BN / 64;
    constexpr int NT = NWR * NWC * 64;
    __shared__ __align__(16) fp16_t ldsA[BM * 32];
    __shared__ __align__(16) fp16_t ldsB[BN * 32];
    const int tid = threadIdx.x;
    const int r0 = bx * BM;
    const int j0 = by * BN;
    const int w = tid >> 6, lane = tid & 63;
    const int wr = w / NWC, wc = w % NWC;
    const int lrow = lane & 15, lg = lane >> 4;

    f32x4 acc[4][4] = {};

    for (int kc = 0; kc < K; kc += 32) {
        __syncthreads();
        const fp16_t* pa;
        int ka, KA;
        if (MODE == 1) {
            KA = HID;
            if (kc >= HID) { pa = A2; ka = kc - HID; }
            else           { pa = A;  ka = kc; }
        } else {
            KA = K; pa = A; ka = kc;
        }
#pragma unroll
        for (int c = tid; c < BM * 4; c += NT) {
            int row = c >> 2, p = c & 3;
            int g = (p - (row >> 1)) & 3;
            int gr = r0 + row; if (gr > N - 1) gr = N - 1;
            gload_lds16(pa + (size_t)gr * KA + ka + g * 8,
                        (char*)ldsA + (size_t)c * 16);
        }
#pragma unroll
        for (int c = tid; c < BN * 4; c += NT) {
            int row = c >> 2, p = c & 3;
            int g = (p - (row >> 1)) & 3;
            gload_lds16(W + (size_t)(j0 + row) * K + kc + g * 8,
                        (char*)ldsB + (size_t)c * 16);
        }
        __syncthreads();

        half8 a[4], b[4];
#pragma unroll
        for (int f = 0; f < 4; ++f) {
            int ar = wr * 64 + f * 16 + lrow;
            int sa = (lg + (ar >> 1)) & 3;
            a[f] = *(const half8*)&ldsA[ar * 32 + sa * 8];
            int br = wc * 64 + f * 16 + lrow;
            int sb = (lg + (br >> 1)) & 3;
            b[f] = *(const half8*)&ldsB[br * 32 + sb * 8];
        }
#pragma unroll
        for (int fi = 0; fi < 4; ++fi)
#pragma unroll
            for (int fj = 0; fj < 4; ++fj)
                acc[fi][fj] = __builtin_amdgcn_mfma_f32_16x16x32_f16(a[fi], b[fj], acc[fi][fj], 0, 0, 0);
    }

    // epilogue: C/D layout col=lane&15, row=(lane>>4)*4+reg
#pragma unroll
    for (int fj = 0; fj < 4; ++fj) {
        int ocol = j0 + wc * 64 + fj * 16 + lrow;
        float bv = bias[ocol];
#pragma unroll
        for (int fi = 0; fi < 4; ++fi) {
#pragma unroll
            for (int r = 0; r < 4; ++r) {
                int orow = r0 + wr * 64 + fi * 16 + lg * 4 + r;
                if (orow < N) {
                    float v = acc[fi][fj][r] + bv;
                    if (RELU) v = fmaxf(v, 0.f);
                    if (WH16) Yh[(size_t)orow * M + ocol] = (fp16_t)v;
                }
            }
        }
    }
}

// ---------------- encoder layer 1 body (K=24, f32 compute, fp16 out; 256 thr, 16 rows) ----
__device__ __forceinline__ void enc1_body(const float* __restrict__ X,
                                          const float* __restrict__ W,
                                          const float* __restrict__ b,
                                          fp16_t* __restrict__ Y, int N, int bx) {
    __shared__ float xs[16][IN_DIM];
    const int tid = threadIdx.x;
    const int row0 = bx * 16;
    for (int i = tid; i < 16 * IN_DIM; i += 256) {
        int r = i / IN_DIM, k = i - r * IN_DIM;
        int gr = row0 + r;
        xs[r][k] = (gr < N) ? X[(size_t)gr * IN_DIM + k] : 0.f;
    }
    __syncthreads();
    const int j = tid & 127;
    const int rg = tid >> 7;   // 0/1: rows rg*8 .. rg*8+7
    float acc[8];
    float bj = b[j];
#pragma unroll
    for (int r = 0; r < 8; ++r) acc[r] = bj;
    for (int k = 0; k < IN_DIM; ++k) {
        float w = W[k * 128 + j];
#pragma unroll
        for (int r = 0; r < 8; ++r) acc[r] = fmaf(xs[rg * 8 + r][k], w, acc[r]);
    }
#pragma unroll
    for (int r = 0; r < 8; ++r) {
        int gr = row0 + rg * 8 + r;
        if (gr < N) Y[(size_t)gr * 128 + j] = (fp16_t)fmaxf(acc[r], 0.f);
    }
}

// ---------------- K1: wtrans (+deg zeroing)  ||  lin_enc1 ----------------
__global__ __launch_bounds__(256) void k_prep(
    const float* __restrict__ enc_w2,
    const float* __restrict__ s1_wl, const float* __restrict__ s1_wr,
    const float* __restrict__ s2_wl, const float* __restrict__ s2_wr,
    const float* __restrict__ ro_w1,
    fp16_t* __restrict__ wtE, fp16_t* __restrict__ wtS1,
    fp16_t* __restrict__ wtS2, fp16_t* __restrict__ wtR,
    int* __restrict__ deg,
    const float* __restrict__ X, const float* __restrict__ enc_w1,
    const float* __restrict__ enc_b1, fp16_t* __restrict__ h0,
    int N, int nbW) {
    const int sE = 256 * 128, sS = 256 * 512, sR = 128 * 256;
    if ((int)blockIdx.x < nbW) {
        int idx = blockIdx.x * 256 + threadIdx.x;
        if (idx < N) deg[idx] = 0;
        float v; fp16_t* p; int o;
        if (idx < sE) {
            int j = idx / 128, k = idx - j * 128;
            v = enc_w2[(size_t)k * 256 + j]; p = wtE; o = idx;
        } else if (idx < sE + sS) {
            int t = idx - sE; int j = t / 512, k = t - j * 512;
            v = (k < 256) ? s1_wl[(size_t)k * 256 + j] : s1_wr[(size_t)(k - 256) * 256 + j];
            p = wtS1; o = t;
        } else if (idx < sE + 2 * sS) {
            int t = idx - sE - sS; int j = t / 512, k = t - j * 512;
            v = (k < 256) ? s2_wl[(size_t)k * 256 + j] : s2_wr[(size_t)(k - 256) * 256 + j];
            p = wtS2; o = t;
        } else if (idx < sE + 2 * sS + sR) {
            int t = idx - sE - 2 * sS; int j = t / 256, k = t - j * 256;
            v = ro_w1[(size_t)k * 128 + j]; p = wtR; o = t;
        } else return;
        p[o] = (fp16_t)v;
    } else {
        enc1_body(X, enc_w1, enc_b1, h0, N, blockIdx.x - nbW);
    }
}

// ---------------- K2: encoder MFMA GEMM  ||  degree count ----------------
__global__ __launch_bounds__(512, 4) void k_encgemm_deg(
    const fp16_t* __restrict__ h0, const fp16_t* __restrict__ wtE,
    const float* __restrict__ enc_b2, fp16_t* __restrict__ hA,
    const int* __restrict__ dst, int* __restrict__ deg,
    int N, int E, int nbGemm) {
    if ((int)blockIdx.x < nbGemm) {
        gemm_body<128, 0, 128, 256, true, true>(h0, nullptr, wtE, enc_b2, hA, N, 256,
                                                blockIdx.x, 0);
    } else {
        int e = (blockIdx.x - nbGemm) * 512 + threadIdx.x;
        if (e < E) atomicAdd(&deg[dst[e]], 1);
    }
}

// ---------------- standalone SAGE GEMM ----------------
template<int K, int MODE, int BM, int BN, bool WH16, bool RELU>
__global__ __launch_bounds__((BM / 64) * (BN / 64) * 64, 4) void gemm_mfma(
    const fp16_t* __restrict__ A, const fp16_t* __restrict__ A2,
    const fp16_t* __restrict__ W,
    const float* __restrict__ bias,
    fp16_t* __restrict__ Yh,
    int N, int M) {
    gemm_body<K, MODE, BM, BN, WH16, RELU>(A, A2, W, bias, Yh, N, M, blockIdx.x, blockIdx.y);
}

// ---------------- Fused readout: out = relu(A @ wtR^T + b1) @ W2 + b2 ----------------
__global__ __launch_bounds__(256, 3) void gemm_ro(
    const fp16_t* __restrict__ A,      // hA [N][256]
    const fp16_t* __restrict__ W,      // wtR [128][256]
    const float* __restrict__ b1,
    const float* __restrict__ W2,      // ro_w2 [128][12] f32
    const float* __restrict__ b2,
    float* __restrict__ out, int N) {
    constexpr int K = 256;
    __shared__ __align__(16) fp16_t ldsA[128 * 32];
    __shared__ __align__(16) fp16_t ldsB[128 * 32];
    __shared__ __align__(16) fp16_t htile[128 * 128];
    __shared__ __align__(16) fp16_t w2t[16 * 128];
    const int tid = threadIdx.x;
    const int r0 = blockIdx.x * 128;
    const int w = tid >> 6, lane = tid & 63;
    const int wr = w >> 1, wc = w & 1;
    const int lrow = lane & 15, lg = lane >> 4;

    for (int i = tid; i < 16 * 128; i += 256) {
        int c = i >> 7, k = i & 127;
        w2t[i] = (c < 12) ? (fp16_t)W2[k * 12 + c] : (fp16_t)0.f;
    }

    f32x4 acc[4][4] = {};
    for (int kc = 0; kc < K; kc += 32) {
        __syncthreads();
#pragma unroll
        for (int c = tid; c < 128 * 4; c += 256) {
            int row = c >> 2, p = c & 3;
            int g = (p - (row >> 1)) & 3;
            int gr = r0 + row; if (gr > N - 1) gr = N - 1;
            gload_lds16(A + (size_t)gr * K + kc + g * 8, (char*)ldsA + (size_t)c * 16);
        }
#pragma unroll
        for (int c = tid; c < 128 * 4; c += 256) {
            int row = c >> 2, p = c & 3;
            int g = (p - (row >> 1)) & 3;
            gload_lds16(W + (size_t)row * K + kc + g * 8, (char*)ldsB + (size_t)c * 16);
        }
        __syncthreads();

        half8 a[4], b[4];
#pragma unroll
        for (int f = 0; f < 4; ++f) {
            int ar = wr * 64 + f * 16 + lrow;
            int sa = (lg + (ar >> 1)) & 3;
            a[f] = *(const half8*)&ldsA[ar * 32 + sa * 8];
            int br = wc * 64 + f * 16 + lrow;
            int sb = (lg + (br >> 1)) & 3;
            b[f] = *(const half8*)&ldsB[br * 32 + sb * 8];
        }
#pragma unroll
        for (int fi = 0; fi < 4; ++fi)
#pragma unroll
            for (int fj = 0; fj < 4; ++fj)
                acc[fi][fj] = __builtin_amdgcn_mfma_f32_16x16x32_f16(a[fi], b[fj], acc[fi][fj], 0, 0, 0);
    }

    // epilogue 1: relu(acc + b1) -> htile (swizzled fp16)
#pragma unroll
    for (int fj = 0; fj < 4; ++fj) {
        int ocol = wc * 64 + fj * 16 + lrow;
        float bv = b1[ocol];
        int q = ocol >> 3;
#pragma unroll
        for (int fi = 0; fi < 4; ++fi) {
#pragma unroll
            for (int r = 0; r < 4; ++r) {
                int orow = wr * 64 + fi * 16 + lg * 4 + r;
                float v = fmaxf(acc[fi][fj][r] + bv, 0.f);
                int phys = (q + (orow >> 1)) & 15;
                htile[orow * 128 + phys * 8 + (ocol & 7)] = (fp16_t)v;
            }
        }
    }
    __syncthreads();

    // final: out(128x12) = htile(128x128) @ W2(128x12); waves 0-1, 64 rows each
    if (w < 2) {
        f32x4 accF[4] = {};
#pragma unroll
        for (int kt = 0; kt < 4; ++kt) {
            half8 bb = *(const half8*)&w2t[lrow * 128 + kt * 32 + lg * 8];
            half8 a[4];
#pragma unroll
            for (int f = 0; f < 4; ++f) {
                int ar = w * 64 + f * 16 + lrow;
                int q = kt * 4 + lg;
                int phys = (q + (ar >> 1)) & 15;
                a[f] = *(const half8*)&htile[ar * 128 + phys * 8];
            }
#pragma unroll
            for (int f = 0; f < 4; ++f)
                accF[f] = __builtin_amdgcn_mfma_f32_16x16x32_f16(a[f], bb, accF[f], 0, 0, 0);
        }
        if (lrow < OUT_DIM) {
            float bv = b2[lrow];
#pragma unroll
            for (int f = 0; f < 4; ++f) {
#pragma unroll
                for (int r = 0; r < 4; ++r) {
                    int orow = r0 + w * 64 + f * 16 + lg * 4 + r;
                    if (orow < N) out[(size_t)orow * OUT_DIM + lrow] = accF[f][r] + bv;
                }
            }
        }
    }
}

// Stage 1: per-block inclusive scan (256 elems/block) + block total
__global__ __launch_bounds__(256) void scan_local(const int* __restrict__ deg,
                                                  int* __restrict__ locincl,
                                                  int* __restrict__ bsum, int N) {
    const int t = threadIdx.x;
    const int i = blockIdx.x * 256 + t;
    int v = (i < N) ? deg[i] : 0;
    const int lane = t & 63;
    int x = v;
#pragma unroll
    for (int off = 1; off < 64; off <<= 1) {
        int y = __shfl_up(x, off, 64);
        if (lane >= off) x += y;
    }
    __shared__ int wsum[4];
    if (lane == 63) wsum[t >> 6] = x;
    __syncthreads();
    const int wid = t >> 6;
    int add = 0;
    for (int wI = 0; wI < wid; ++wI) add += wsum[wI];
    x += add;
    if (i < N) locincl[i] = x;
    if (t == 255) bsum[blockIdx.x] = x;
}

// Stage 2: each block reduces bsum[0..blockIdx.x) itself, writes exclusive rowptr + cursor.
__global__ __launch_bounds__(256) void scan_final(const int* __restrict__ deg,
                                                  const int* __restrict__ locincl,
                                                  const int* __restrict__ bsum,
                                                  int* __restrict__ rowptr,
                                                  int* __restrict__ cursor,
                                                  int N, int E, int B) {
    __shared__ int red[4];
    const int t = threadIdx.x;
    int s = (t < blockIdx.x && t < B) ? bsum[t] : 0;
#pragma unroll
    for (int off = 32; off > 0; off >>= 1) s += __shfl_down(s, off, 64);
    if ((t & 63) == 0) red[t >> 6] = s;
    __syncthreads();
    int base = red[0] + red[1] + red[2] + red[3];
    const int i = blockIdx.x * 256 + t;
    if (i < N) {
        int excl = base + locincl[i] - deg[i];
        rowptr[i] = excl;
        cursor[i] = excl;
    }
    if (i == 0) rowptr[N] = E;
}

__global__ void scatter_kernel(const int* __restrict__ src, const int* __restrict__ dst,
                               int* __restrict__ cursor, int* __restrict__ esrc, int E) {
    int e = blockIdx.x * blockDim.x + threadIdx.x;
    if (e < E) {
        int pos = atomicAdd(&cursor[dst[e]], 1);
        esrc[pos] = src[e];
    }
}

// ---------------- CSR mean-aggregation: wave-per-node, 16B/lane gathers ----------------
// 2x-unrolled edge loop per half-wave: 4 independent row-gathers in flight per wave.
__global__ __launch_bounds__(256) void agg_csr(const fp16_t* __restrict__ h,
                                               const int* __restrict__ rowptr,
                                               const int* __restrict__ esrc,
                                               fp16_t* __restrict__ mean, int N) {
    const int n = blockIdx.x * 4 + (threadIdx.x >> 6);
    if (n >= N) return;
    const int lane = threadIdx.x & 63;
    const int half = lane >> 5;         // 0 or 1
    const int l32 = lane & 31;          // channel group 0..31 (8 ch each)
    const int r0 = rowptr[n];
    const int r1 = rowptr[n + 1];
    const int deg = r1 - r0;

    float acc[8];
#pragma unroll
    for (int j = 0; j < 8; ++j) acc[j] = 0.f;

    int e = r0 + half;
    // 2 edges in flight per half-wave (4 per wave)
    for (; e + 2 < r1; e += 4) {
        int s0 = esrc[e];
        int s1 = esrc[e + 2];
        half8 v0 = *(const half8*)&h[(size_t)s0 * HID + l32 * 8];
        half8 v1 = *(const half8*)&h[(size_t)s1 * HID + l32 * 8];
#pragma unroll
        for (int j = 0; j < 8; ++j) acc[j] += (float)v0[j] + (float)v1[j];
    }
    for (; e < r1; e += 2) {
        int s = esrc[e];
        half8 v = *(const half8*)&h[(size_t)s * HID + l32 * 8];
#pragma unroll
        for (int j = 0; j < 8; ++j) acc[j] += (float)v[j];
    }
#pragma unroll
    for (int j = 0; j < 8; ++j) acc[j] += __shfl(acc[j], lane ^ 32, 64);

    if (half == 0) {
        float inv = 1.0f / fmaxf((float)deg, 1.0f);
        half8 o;
#pragma unroll
        for (int j = 0; j < 8; ++j) o[j] = (fp16_t)(acc[j] * inv);
        *(half8*)&mean[(size_t)n * HID + l32 * 8] = o;
    }
}

extern "C" void kernel_launch(void* const* d_in, const int* in_sizes, int n_in,
                              void* d_out, int out_size, void* d_ws, size_t ws_size,
                              hipStream_t stream) {
    const float* x      = (const float*)d_in[0];
    const int*   eidx   = (const int*)d_in[1];
    const float* enc_w1 = (const float*)d_in[2];
    const float* enc_b1 = (const float*)d_in[3];
    const float* enc_w2 = (const float*)d_in[4];
    const float* enc_b2 = (const float*)d_in[5];
    const float* s1_wl  = (const float*)d_in[6];
    const float* s1_bl  = (const float*)d_in[7];
    const float* s1_wr  = (const float*)d_in[8];
    const float* s2_wl  = (const float*)d_in[9];
    const float* s2_bl  = (const float*)d_in[10];
    const float* s2_wr  = (const float*)d_in[11];
    const float* ro_w1  = (const float*)d_in[12];
    const float* ro_b1  = (const float*)d_in[13];
    const float* ro_w2  = (const float*)d_in[14];
    const float* ro_b2  = (const float*)d_in[15];
    float* out = (float*)d_out;

    const int N = N_NODES;
    const int E = N_EDGES;
    const int* src = eidx;
    const int* dst = eidx + E;

    char* ws = (char*)d_ws;
    size_t off = 0;
    auto alloc = [&](size_t bytes) { void* p = ws + off; off += (bytes + 255) & ~255ULL; return p; };
    int* deg     = (int*)alloc((size_t)N * 4);
    int* rowptr  = (int*)alloc((size_t)(N + 1) * 4);
    int* cursor  = (int*)alloc((size_t)N * 4);
    int* esrc    = (int*)alloc((size_t)E * 4);
    int* locincl = (int*)alloc((size_t)N * 4);
    int* bsum    = (int*)alloc((size_t)256 * 4);
    fp16_t* wtE  = (fp16_t*)alloc((size_t)256 * 128 * 2);
    fp16_t* wtS1 = (fp16_t*)alloc((size_t)256 * 512 * 2);
    fp16_t* wtS2 = (fp16_t*)alloc((size_t)256 * 512 * 2);
    fp16_t* wtR  = (fp16_t*)alloc((size_t)128 * 256 * 2);
    fp16_t* h0   = (fp16_t*)alloc((size_t)N * 128 * 2);
    fp16_t* hA   = (fp16_t*)alloc((size_t)N * HID * 2);
    fp16_t* hB   = (fp16_t*)alloc((size_t)N * HID * 2);
    fp16_t* mbuf = (fp16_t*)alloc((size_t)N * HID * 2);

    const int gx128 = (N + 127) / 128;
    const int nbScan = (N + 255) / 256;
    const int nbAgg = (N + 3) / 4;
    const int wtTot = 256 * 128 + 2 * 256 * 512 + 128 * 256;
    const int nbW = (wtTot + 255) / 256;           // 1568
    const int nbEnc = (N + 15) / 16;               // 3125
    const int nbDeg512 = (E + 511) / 512;          // 782

    // ---- K1: wtrans (+deg zero)  ||  lin_enc1 ----
    k_prep<<<nbW + nbEnc, 256, 0, stream>>>(
        enc_w2, s1_wl, s1_wr, s2_wl, s2_wr, ro_w1,
        wtE, wtS1, wtS2, wtR, deg, x, enc_w1, enc_b1, h0, N, nbW);

    // ---- K2: encoder GEMM  ||  degree count ----
    k_encgemm_deg<<<gx128 + nbDeg512, 512, 0, stream>>>(
        h0, wtE, enc_b2, hA, dst, deg, N, E, gx128);

    // ---- CSR scan + scatter ----
    scan_local<<<nbScan, 256, 0, stream>>>(deg, locincl, bsum, N);
    scan_final<<<nbScan, 256, 0, stream>>>(deg, locincl, bsum, rowptr, cursor, N, E, nbScan);
    scatter_kernel<<<(E + 255) / 256, 256, 0, stream>>>(src, dst, cursor, esrc, E);

    // ---- SAGE 1 ----
    agg_csr<<<nbAgg, 256, 0, stream>>>(hA, rowptr, esrc, mbuf, N);
    gemm_mfma<512, 1, 128, 256, true, true><<<dim3(gx128, 1), 512, 0, stream>>>(
        mbuf, hA, wtS1, s1_bl, hB, N, 256);

    // ---- SAGE 2 ----
    agg_csr<<<nbAgg, 256, 0, stream>>>(hB, rowptr, esrc, mbuf, N);
    gemm_mfma<512, 1, 128, 256, true, true><<<dim3(gx128, 1), 512, 0, stream>>>(
        mbuf, hB, wtS2, s2_bl, hA, N, 256);

    // ---- fused readout ----
    gemm_ro<<<gx128, 256, 0, stream>>>(hA, wtR, ro_b1, ro_w2, ro_b2, out, N);
}